// Round 5
// baseline (51.434 us; speedup 1.0000x reference)
//
#include <hip/hip_runtime.h>
#include <hip/hip_bf16.h>

#define NUM_HEADS 16
#define HEAD_DIM  64
#define HD        1024   // NUM_HEADS*HEAD_DIM
#define SEQL      1024
#define NTILE     16     // kv tiles per sequence
#define TILE_E    4096   // elements per 64x64 bf16 tile (8 KB)
#define HSTRIDE   (64 * TILE_E)          // 64 tiles per head
#define VT_OFF    (NUM_HEADS * HSTRIDE)  // V-fragment array offset in ws (elems)
#define FIXED_M   12.0f                  // fixed log2-domain shift (max score ~8 sigma)

typedef __bf16 bf16x8 __attribute__((ext_vector_type(8)));
typedef float  f32x4  __attribute__((ext_vector_type(4)));

#define MFMA16(A, B, C) __builtin_amdgcn_mfma_f32_16x16x32_bf16((A), (B), (C), 0, 0, 0)

// ---------------- prep: fp32 K,V -> bf16 PER-FRAGMENT-CONTIGUOUS blocks ----------------
// K tile: fragment f = t*2+c (t: kv 16-row group, c: k-chunk) is a 1KB span;
//   lane l=(g,a): 8 elems = K[kv0+16t+a][d = 32c+8g .. +8]
// V tile: fragment f = dt*2+c is a 1KB span;
//   lane l=(g,a): elem e = V[kv0 + 32c+16(e>>2)+4g+(e&3)][d = 16dt+a]
__global__ __launch_bounds__(256)
void prep_kernel(const float* __restrict__ K, const float* __restrict__ V,
                 __bf16* __restrict__ ws)
{
    __shared__ __bf16 v_s[64][72];
    const int tid  = threadIdx.x;
    const int tile = blockIdx.x;   // 0..63 global kv tile (seq*16 + it)
    const int h    = blockIdx.y;
    const int kv0  = tile * 64;
    __bf16* kb = ws + (size_t)h * HSTRIDE + (size_t)tile * TILE_E;
    __bf16* vt = ws + VT_OFF + (size_t)h * HSTRIDE + (size_t)tile * TILE_E;

    #pragma unroll
    for (int i = 0; i < 2; ++i) {
        const int c2 = tid + 256 * i;      // chunk id 0..511
        const int f  = c2 >> 6;            // fragment 0..7
        const int l  = c2 & 63;
        const int g  = l >> 4, aa = l & 15;
        const int t  = f >> 1, cc = f & 1;
        const int r  = 16 * t + aa;        // covers 0..63 exactly once per d-chunk
        const int d0 = 32 * cc + 8 * g;    // covers 0,8,...,56

        const float* kp = K + (size_t)(kv0 + r) * HD + h * HEAD_DIM + d0;
        float4 f0 = *(const float4*)kp, f1 = *(const float4*)(kp + 4);
        bf16x8 u = {(__bf16)f0.x, (__bf16)f0.y, (__bf16)f0.z, (__bf16)f0.w,
                    (__bf16)f1.x, (__bf16)f1.y, (__bf16)f1.z, (__bf16)f1.w};
        *reinterpret_cast<bf16x8*>(kb + f * 512 + l * 8) = u;

        const float* vp = V + (size_t)(kv0 + r) * HD + h * HEAD_DIM + d0;
        float4 g0 = *(const float4*)vp, g1 = *(const float4*)(vp + 4);
        bf16x8 w = {(__bf16)g0.x, (__bf16)g0.y, (__bf16)g0.z, (__bf16)g0.w,
                    (__bf16)g1.x, (__bf16)g1.y, (__bf16)g1.z, (__bf16)g1.w};
        *reinterpret_cast<bf16x8*>(&v_s[r][d0]) = w;
    }
    __syncthreads();
    #pragma unroll
    for (int i = 0; i < 2; ++i) {
        const int c2 = tid + 256 * i;
        const int f  = c2 >> 6;            // fragment 0..7: dt = f>>1, c = f&1
        const int l  = c2 & 63;
        const int g  = l >> 4, aa = l & 15;
        const int dt = f >> 1, cc = f & 1;
        const int d  = 16 * dt + aa;
        bf16x8 w;
        #pragma unroll
        for (int e = 0; e < 8; ++e) {
            const int kvl = 32 * cc + ((e >> 2) << 4) + 4 * g + (e & 3);
            w[e] = v_s[kvl][d];
        }
        *reinterpret_cast<bf16x8*>(vt + f * 512 + l * 8) = w;
    }
}

// ---------------- attention: NO LDS, fragments direct from global (L1/L2) ----------------
__global__ __launch_bounds__(256)
void fattn5_kernel(const float* __restrict__ Q, const __bf16* __restrict__ ws,
                   float* __restrict__ O)
{
    const int tid  = threadIdx.x;
    const int lane = tid & 63;
    const int wave = tid >> 6;
    const int g    = lane >> 4;
    const int a    = lane & 15;

    // bijective XCD-chunked mapping: each XCD gets 8 complete (h,seq) groups of 16 blocks
    const int b     = blockIdx.x;
    const int orig  = (b & 7) * 128 + (b >> 3);
    const int group = orig >> 4;          // h*4 + seq
    const int qt    = orig & 15;
    const int h     = group >> 2;
    const int seq   = group & 3;
    const int q0    = seq * SEQL + qt * 64;

    const __bf16* kb_base = ws + (size_t)h * HSTRIDE + (size_t)seq * NTILE * TILE_E;
    const __bf16* vt_base = ws + VT_OFF + (size_t)h * HSTRIDE + (size_t)seq * NTILE * TILE_E;

    const float qscale = 0.125f * 1.44269504088896340736f; // 1/sqrt(64) * log2(e)

    // Q fragments: lane holds Q row (wave*16 + a), d = 8g + 32c + [0..8)
    bf16x8 qf[2];
    {
        const float* qp = Q + (size_t)(q0 + wave * 16 + a) * HD + h * HEAD_DIM + g * 8;
        #pragma unroll
        for (int c = 0; c < 2; ++c) {
            float4 f0 = *reinterpret_cast<const float4*>(qp + 32 * c);
            float4 f1 = *reinterpret_cast<const float4*>(qp + 32 * c + 4);
            qf[c][0] = (__bf16)(f0.x * qscale); qf[c][1] = (__bf16)(f0.y * qscale);
            qf[c][2] = (__bf16)(f0.z * qscale); qf[c][3] = (__bf16)(f0.w * qscale);
            qf[c][4] = (__bf16)(f1.x * qscale); qf[c][5] = (__bf16)(f1.y * qscale);
            qf[c][6] = (__bf16)(f1.z * qscale); qf[c][7] = (__bf16)(f1.w * qscale);
        }
    }

    f32x4 o_acc[4];
    #pragma unroll
    for (int dt = 0; dt < 4; ++dt) o_acc[dt] = (f32x4){0.f, 0.f, 0.f, 0.f};
    f32x4 l_acc = (f32x4){0.f, 0.f, 0.f, 0.f};

    bf16x8 ones;
    #pragma unroll
    for (int e = 0; e < 8; ++e) ones[e] = (__bf16)1.0f;

    const f32x4 minit = (f32x4){-FIXED_M, -FIXED_M, -FIXED_M, -FIXED_M};
    const int loff = lane * 8;   // this lane's 8-elem slot within a 512-elem fragment

    #pragma unroll 2
    for (int it = 0; it < NTILE; ++it) {
        const __bf16* kb = kb_base + (size_t)it * TILE_E;
        const __bf16* vb = vt_base + (size_t)it * TILE_E;

        // issue all fragment loads up front (coalesced 1KB spans; L1 broadcasts across waves)
        bf16x8 kf[8], vf[8];
        #pragma unroll
        for (int f = 0; f < 8; ++f) kf[f] = *reinterpret_cast<const bf16x8*>(kb + f * 512 + loff);
        #pragma unroll
        for (int f = 0; f < 8; ++f) vf[f] = *reinterpret_cast<const bf16x8*>(vb + f * 512 + loff);

        // ---- QK^T (swapped): s[t][r] = S^T[kv=16t+4g+r][q=a] - FIXED_M ----
        f32x4 s[4];
        __builtin_amdgcn_s_setprio(1);
        #pragma unroll
        for (int t = 0; t < 4; ++t) {
            s[t] = MFMA16(kf[2 * t],     qf[0], minit);
            s[t] = MFMA16(kf[2 * t + 1], qf[1], s[t]);
        }
        __builtin_amdgcn_s_setprio(0);

        // ---- fixed-shift softmax: p = exp2(s) via raw v_exp_f32 ----
        // pf[c] elem b -> kv = 32c + 16(b>>2) + 4g + (b&3)
        bf16x8 pf[2];
        #pragma unroll
        for (int c = 0; c < 2; ++c)
            #pragma unroll
            for (int bb = 0; bb < 8; ++bb)
                pf[c][bb] = (__bf16)__builtin_amdgcn_exp2f(s[2 * c + (bb >> 2)][bb & 3]);

        // ---- PV + l row-sum (ones B-fragment), all on the MFMA pipe ----
        __builtin_amdgcn_s_setprio(1);
        l_acc = MFMA16(pf[0], ones, l_acc);
        l_acc = MFMA16(pf[1], ones, l_acc);
        #pragma unroll
        for (int dt = 0; dt < 4; ++dt) {
            o_acc[dt] = MFMA16(pf[0], vf[2 * dt],     o_acc[dt]);
            o_acc[dt] = MFMA16(pf[1], vf[2 * dt + 1], o_acc[dt]);
        }
        __builtin_amdgcn_s_setprio(0);
    }

    // ---- epilogue: O rows q = 4g+r, cols d = 16dt + a; l_acc row-aligned ----
    #pragma unroll
    for (int r = 0; r < 4; ++r) {
        const float inv = 1.0f / l_acc[r];
        float* op = O + (size_t)(q0 + wave * 16 + 4 * g + r) * HD + h * HEAD_DIM + a;
        #pragma unroll
        for (int dt = 0; dt < 4; ++dt)
            op[16 * dt] = o_acc[dt][r] * inv;
    }
}

extern "C" void kernel_launch(void* const* d_in, const int* in_sizes, int n_in,
                              void* d_out, int out_size, void* d_ws, size_t ws_size,
                              hipStream_t stream) {
    const float* q = (const float*)d_in[0];
    const float* k = (const float*)d_in[1];
    const float* v = (const float*)d_in[2];
    float* out = (float*)d_out;
    __bf16* ws = (__bf16*)d_ws;   // 16 MB: 8 MB K-fragments + 8 MB V-fragments

    dim3 pgrid(64, NUM_HEADS);
    prep_kernel<<<pgrid, 256, 0, stream>>>(k, v, ws);
    fattn5_kernel<<<1024, 256, 0, stream>>>(q, ws, out);
}

// Round 6
// 40.501 us; speedup vs baseline: 1.2700x; 1.2700x over previous
//
#include <hip/hip_runtime.h>
#include <hip/hip_bf16.h>

#define NUM_HEADS 16
#define HEAD_DIM  64
#define HD        1024   // NUM_HEADS*HEAD_DIM
#define SEQL      1024
#define NTILE     16     // kv tiles per sequence
#define TILE_E    4096   // elements per 64x64 bf16 tile (8 KB)
#define HSTRIDE   (64 * TILE_E)          // 64 tiles per head
#define VT_OFF    (NUM_HEADS * HSTRIDE)  // V-fragment array offset in ws (elems)
#define FIXED_M   12.0f                  // fixed log2-domain shift (max score ~8 sigma)

typedef __bf16 bf16x8 __attribute__((ext_vector_type(8)));
typedef float  f32x4  __attribute__((ext_vector_type(4)));

#define MFMA16(A, B, C) __builtin_amdgcn_mfma_f32_16x16x32_bf16((A), (B), (C), 0, 0, 0)
#define GLOAD_LDS16(gp, lp) \
  __builtin_amdgcn_global_load_lds((const __attribute__((address_space(1))) void*)(gp), \
                                   (__attribute__((address_space(3))) void*)(lp), 16, 0, 0)

// ---------------- prep: fp32 K,V -> bf16 PER-FRAGMENT-CONTIGUOUS tiles ----------------
// K tile: fragment f = t*2+c is a contiguous 1KB span (512 elems);
//   lane l=(g,a): 8 elems = K[kv0+16t+a][d = 32c+8g .. +8]
// V tile: fragment f = dt*2+c contiguous 1KB;
//   lane l=(g,a): elem e = V[kv0 + 32c+16(e>>2)+4g+(e&3)][d = 16dt+a]
__global__ __launch_bounds__(256)
void prep_kernel(const float* __restrict__ K, const float* __restrict__ V,
                 __bf16* __restrict__ ws)
{
    __shared__ __bf16 v_s[64][72];
    const int tid  = threadIdx.x;
    const int tile = blockIdx.x;   // 0..63 global kv tile (seq*16 + it)
    const int h    = blockIdx.y;
    const int kv0  = tile * 64;
    __bf16* kb = ws + (size_t)h * HSTRIDE + (size_t)tile * TILE_E;
    __bf16* vt = ws + VT_OFF + (size_t)h * HSTRIDE + (size_t)tile * TILE_E;

    #pragma unroll
    for (int i = 0; i < 2; ++i) {
        const int c2 = tid + 256 * i;      // chunk id 0..511
        const int f  = c2 >> 6;            // fragment 0..7
        const int l  = c2 & 63;
        const int g  = l >> 4, aa = l & 15;
        const int t  = f >> 1, cc = f & 1;
        const int r  = 16 * t + aa;
        const int d0 = 32 * cc + 8 * g;

        const float* kp = K + (size_t)(kv0 + r) * HD + h * HEAD_DIM + d0;
        float4 f0 = *(const float4*)kp, f1 = *(const float4*)(kp + 4);
        bf16x8 u = {(__bf16)f0.x, (__bf16)f0.y, (__bf16)f0.z, (__bf16)f0.w,
                    (__bf16)f1.x, (__bf16)f1.y, (__bf16)f1.z, (__bf16)f1.w};
        *reinterpret_cast<bf16x8*>(kb + f * 512 + l * 8) = u;

        const float* vp = V + (size_t)(kv0 + r) * HD + h * HEAD_DIM + d0;
        float4 g0 = *(const float4*)vp, g1 = *(const float4*)(vp + 4);
        bf16x8 w = {(__bf16)g0.x, (__bf16)g0.y, (__bf16)g0.z, (__bf16)g0.w,
                    (__bf16)g1.x, (__bf16)g1.y, (__bf16)g1.z, (__bf16)g1.w};
        *reinterpret_cast<bf16x8*>(&v_s[r][d0]) = w;
    }
    __syncthreads();
    #pragma unroll
    for (int i = 0; i < 2; ++i) {
        const int c2 = tid + 256 * i;
        const int f  = c2 >> 6;            // fragment: dt = f>>1, c = f&1
        const int l  = c2 & 63;
        const int g  = l >> 4, aa = l & 15;
        const int dt = f >> 1, cc = f & 1;
        const int d  = 16 * dt + aa;
        bf16x8 w;
        #pragma unroll
        for (int e = 0; e < 8; ++e) {
            const int kvl = 32 * cc + ((e >> 2) << 4) + 4 * g + (e & 3);
            w[e] = v_s[kvl][d];
        }
        *reinterpret_cast<bf16x8*>(vt + f * 512 + l * 8) = w;
    }
}

// ---------------- attention: QR=32/wave, LDS staged, fragment-contiguous ----------------
__global__ __launch_bounds__(256)
void fattn6_kernel(const float* __restrict__ Q, const __bf16* __restrict__ ws,
                   float* __restrict__ O)
{
    __shared__ __bf16 kbuf[2][TILE_E];   // 2 x 8KB double buffer
    __shared__ __bf16 vbuf[2][TILE_E];

    const int tid  = threadIdx.x;
    const int lane = tid & 63;
    const int wave = tid >> 6;
    const int g    = lane >> 4;
    const int a    = lane & 15;

    // 512 blocks; bijective XCD chunking: XCD x gets orig in [x*64, x*64+64)
    // = 8 complete (h,seq) groups of 8 q-blocks -> K/V reuse stays in one L2
    const int b     = blockIdx.x;
    const int orig  = (b & 7) * 64 + (b >> 3);
    const int group = orig >> 3;          // h*4 + seq (0..63)
    const int qb    = orig & 7;           // q-block within sequence (0..7)
    const int h     = group >> 2;
    const int seq   = group & 3;
    const int q0    = seq * SEQL + qb * 128;   // block owns 128 q rows; wave owns 32

    const __bf16* kb_base = ws + (size_t)h * HSTRIDE + (size_t)seq * NTILE * TILE_E;
    const __bf16* vt_base = ws + VT_OFF + (size_t)h * HSTRIDE + (size_t)seq * NTILE * TILE_E;

    const float qscale = 0.125f * 1.44269504088896340736f; // 1/sqrt(64) * log2(e)

    // Q fragments for 2 q-subtiles: row = q0 + wave*32 + u*16 + a, d = 8g + 32c + [0..8)
    bf16x8 qf[2][2];
    #pragma unroll
    for (int u = 0; u < 2; ++u) {
        const float* qp = Q + (size_t)(q0 + wave * 32 + u * 16 + a) * HD + h * HEAD_DIM + g * 8;
        #pragma unroll
        for (int c = 0; c < 2; ++c) {
            float4 f0 = *reinterpret_cast<const float4*>(qp + 32 * c);
            float4 f1 = *reinterpret_cast<const float4*>(qp + 32 * c + 4);
            qf[u][c][0] = (__bf16)(f0.x * qscale); qf[u][c][1] = (__bf16)(f0.y * qscale);
            qf[u][c][2] = (__bf16)(f0.z * qscale); qf[u][c][3] = (__bf16)(f0.w * qscale);
            qf[u][c][4] = (__bf16)(f1.x * qscale); qf[u][c][5] = (__bf16)(f1.y * qscale);
            qf[u][c][6] = (__bf16)(f1.z * qscale); qf[u][c][7] = (__bf16)(f1.w * qscale);
        }
    }

    f32x4 o_acc[2][4];
    #pragma unroll
    for (int u = 0; u < 2; ++u)
        #pragma unroll
        for (int dt = 0; dt < 4; ++dt) o_acc[u][dt] = (f32x4){0.f, 0.f, 0.f, 0.f};
    f32x4 l_acc[2] = {(f32x4){0.f, 0.f, 0.f, 0.f}, (f32x4){0.f, 0.f, 0.f, 0.f}};

    bf16x8 ones;
    #pragma unroll
    for (int e = 0; e < 8; ++e) ones[e] = (__bf16)1.0f;

    const f32x4 minit = (f32x4){-FIXED_M, -FIXED_M, -FIXED_M, -FIXED_M};
    const int lb = lane * 16;            // lane's byte slot within a 1KB fragment

    const int stid8 = tid * 8;
    auto stage = [&](int buf, int t) {
        const __bf16* ks = kb_base + (size_t)t * TILE_E + stid8;
        const __bf16* vs = vt_base + (size_t)t * TILE_E + stid8;
        GLOAD_LDS16(ks,        &kbuf[buf][stid8]);
        GLOAD_LDS16(ks + 2048, &kbuf[buf][2048 + stid8]);
        GLOAD_LDS16(vs,        &vbuf[buf][stid8]);
        GLOAD_LDS16(vs + 2048, &vbuf[buf][2048 + stid8]);
    };

    auto body = [&](int it, const int buf) {
        if (it < NTILE - 1) stage(buf ^ 1, it + 1);  // prefetch overlaps compute

        const char* kc = (const char*)&kbuf[buf][0];
        const char* vc = (const char*)&vbuf[buf][0];

        // ---- QK^T (swapped), both q-subtiles share each K fragment read ----
        // s[u][t][r] = S^T[kv=16t+4g+r][q=a] - FIXED_M   (fragment f=2t+c at byte f*1024+lane*16)
        f32x4 s[2][4];
        __builtin_amdgcn_s_setprio(1);
        #pragma unroll
        for (int t = 0; t < 4; ++t) {
            bf16x8 kf0 = *reinterpret_cast<const bf16x8*>(kc + (2 * t)     * 1024 + lb);
            bf16x8 kf1 = *reinterpret_cast<const bf16x8*>(kc + (2 * t + 1) * 1024 + lb);
            #pragma unroll
            for (int u = 0; u < 2; ++u) {
                s[u][t] = MFMA16(kf0, qf[u][0], minit);
                s[u][t] = MFMA16(kf1, qf[u][1], s[u][t]);
            }
        }
        __builtin_amdgcn_s_setprio(0);

        // ---- fixed-shift softmax: p = exp2(s), raw v_exp_f32 ----
        bf16x8 pf[2][2];
        #pragma unroll
        for (int u = 0; u < 2; ++u)
            #pragma unroll
            for (int c = 0; c < 2; ++c)
                #pragma unroll
                for (int bb = 0; bb < 8; ++bb)
                    pf[u][c][bb] = (__bf16)__builtin_amdgcn_exp2f(s[u][2 * c + (bb >> 2)][bb & 3]);

        // ---- l row-sum + PV, V fragments shared across both q-subtiles ----
        __builtin_amdgcn_s_setprio(1);
        #pragma unroll
        for (int u = 0; u < 2; ++u) {
            l_acc[u] = MFMA16(pf[u][0], ones, l_acc[u]);
            l_acc[u] = MFMA16(pf[u][1], ones, l_acc[u]);
        }
        #pragma unroll
        for (int dt = 0; dt < 4; ++dt) {
            bf16x8 vf0 = *reinterpret_cast<const bf16x8*>(vc + (2 * dt)     * 1024 + lb);
            bf16x8 vf1 = *reinterpret_cast<const bf16x8*>(vc + (2 * dt + 1) * 1024 + lb);
            #pragma unroll
            for (int u = 0; u < 2; ++u) {
                o_acc[u][dt] = MFMA16(pf[u][0], vf0, o_acc[u][dt]);
                o_acc[u][dt] = MFMA16(pf[u][1], vf1, o_acc[u][dt]);
            }
        }
        __builtin_amdgcn_s_setprio(0);

        __syncthreads();  // drains prefetch vmcnt + lgkm; safe to flip buffers
    };

    stage(0, 0);
    __syncthreads();

    #pragma unroll 1
    for (int it2 = 0; it2 < NTILE / 2; ++it2) {
        body(2 * it2,     0);
        body(2 * it2 + 1, 1);
    }

    // ---- epilogue: O rows q = wave*32 + u*16 + 4g + r, cols d = 16dt + a ----
    #pragma unroll
    for (int u = 0; u < 2; ++u)
        #pragma unroll
        for (int r = 0; r < 4; ++r) {
            const float inv = 1.0f / l_acc[u][r];
            float* op = O + (size_t)(q0 + wave * 32 + u * 16 + 4 * g + r) * HD + h * HEAD_DIM + a;
            #pragma unroll
            for (int dt = 0; dt < 4; ++dt)
                op[16 * dt] = o_acc[u][dt][r] * inv;
        }
}

extern "C" void kernel_launch(void* const* d_in, const int* in_sizes, int n_in,
                              void* d_out, int out_size, void* d_ws, size_t ws_size,
                              hipStream_t stream) {
    const float* q = (const float*)d_in[0];
    const float* k = (const float*)d_in[1];
    const float* v = (const float*)d_in[2];
    float* out = (float*)d_out;
    __bf16* ws = (__bf16*)d_ws;   // 16 MB: 8 MB K-fragments + 8 MB V-fragments

    dim3 pgrid(64, NUM_HEADS);
    prep_kernel<<<pgrid, 256, 0, stream>>>(k, v, ws);
    fattn6_kernel<<<512, 256, 0, stream>>>(q, ws, out);
}

// Round 7
// 40.079 us; speedup vs baseline: 1.2833x; 1.0105x over previous
//
#include <hip/hip_runtime.h>
#include <hip/hip_bf16.h>

#define NUM_HEADS 16
#define HEAD_DIM  64
#define HD        1024   // NUM_HEADS*HEAD_DIM
#define SEQL      1024
#define NTILE     16     // kv tiles per sequence
#define TILE_E    4096   // elements per 64x64 bf16 tile (8 KB)
#define HSTRIDE   (64 * TILE_E)          // 64 tiles per head
#define VT_OFF    (NUM_HEADS * HSTRIDE)  // V-fragment array offset in ws (elems)
#define FIXED_M   12.0f                  // fixed log2-domain shift (max score ~8 sigma)

typedef __bf16 bf16x8 __attribute__((ext_vector_type(8)));
typedef float  f32x4  __attribute__((ext_vector_type(4)));

#define MFMA16(A, B, C) __builtin_amdgcn_mfma_f32_16x16x32_bf16((A), (B), (C), 0, 0, 0)

// ---------------- prep: fp32 K,V -> bf16 PER-FRAGMENT-CONTIGUOUS tiles ----------------
// K tile: fragment f = t*2+c is a contiguous 1KB span (512 elems);
//   lane l=(g,a): 8 elems = K[kv0+16t+a][d = 32c+8g .. +8]
// V tile: fragment f = dt*2+c contiguous 1KB;
//   lane l=(g,a): elem e = V[kv0 + 32c+16(e>>2)+4g+(e&3)][d = 16dt+a]
__global__ __launch_bounds__(256)
void prep_kernel(const float* __restrict__ K, const float* __restrict__ V,
                 __bf16* __restrict__ ws)
{
    __shared__ __bf16 v_s[64][72];
    const int tid  = threadIdx.x;
    const int tile = blockIdx.x;   // 0..63 global kv tile (seq*16 + it)
    const int h    = blockIdx.y;
    const int kv0  = tile * 64;
    __bf16* kb = ws + (size_t)h * HSTRIDE + (size_t)tile * TILE_E;
    __bf16* vt = ws + VT_OFF + (size_t)h * HSTRIDE + (size_t)tile * TILE_E;

    #pragma unroll
    for (int i = 0; i < 2; ++i) {
        const int c2 = tid + 256 * i;      // chunk id 0..511
        const int f  = c2 >> 6;            // fragment 0..7
        const int l  = c2 & 63;
        const int g  = l >> 4, aa = l & 15;
        const int t  = f >> 1, cc = f & 1;
        const int r  = 16 * t + aa;
        const int d0 = 32 * cc + 8 * g;

        const float* kp = K + (size_t)(kv0 + r) * HD + h * HEAD_DIM + d0;
        float4 f0 = *(const float4*)kp, f1 = *(const float4*)(kp + 4);
        bf16x8 u = {(__bf16)f0.x, (__bf16)f0.y, (__bf16)f0.z, (__bf16)f0.w,
                    (__bf16)f1.x, (__bf16)f1.y, (__bf16)f1.z, (__bf16)f1.w};
        *reinterpret_cast<bf16x8*>(kb + f * 512 + l * 8) = u;

        const float* vp = V + (size_t)(kv0 + r) * HD + h * HEAD_DIM + d0;
        float4 g0 = *(const float4*)vp, g1 = *(const float4*)(vp + 4);
        bf16x8 w = {(__bf16)g0.x, (__bf16)g0.y, (__bf16)g0.z, (__bf16)g0.w,
                    (__bf16)g1.x, (__bf16)g1.y, (__bf16)g1.z, (__bf16)g1.w};
        *reinterpret_cast<bf16x8*>(&v_s[r][d0]) = w;
    }
    __syncthreads();
    #pragma unroll
    for (int i = 0; i < 2; ++i) {
        const int c2 = tid + 256 * i;
        const int f  = c2 >> 6;            // fragment: dt = f>>1, c = f&1
        const int l  = c2 & 63;
        const int g  = l >> 4, aa = l & 15;
        const int dt = f >> 1, cc = f & 1;
        const int d  = 16 * dt + aa;
        bf16x8 w;
        #pragma unroll
        for (int e = 0; e < 8; ++e) {
            const int kvl = 32 * cc + ((e >> 2) << 4) + 4 * g + (e & 3);
            w[e] = v_s[kvl][d];
        }
        *reinterpret_cast<bf16x8*>(vt + f * 512 + l * 8) = w;
    }
}

// ---------------- attention: NO LDS, no barriers, QR=32 q-rows per wave ----------------
__global__ __launch_bounds__(256)
void fattn7_kernel(const float* __restrict__ Q, const __bf16* __restrict__ ws,
                   float* __restrict__ O)
{
    const int tid  = threadIdx.x;
    const int lane = tid & 63;
    const int wave = tid >> 6;
    const int g    = lane >> 4;
    const int a    = lane & 15;

    // 512 blocks; bijective XCD chunking: XCD x gets orig in [x*64, x*64+64)
    // = 8 complete (h,seq) groups of 8 q-blocks -> 2 MB working set per XCD L2
    const int b     = blockIdx.x;
    const int orig  = (b & 7) * 64 + (b >> 3);
    const int group = orig >> 3;          // h*4 + seq (0..63)
    const int qb    = orig & 7;           // q-block within sequence (0..7)
    const int h     = group >> 2;
    const int seq   = group & 3;
    const int q0    = seq * SEQL + qb * 128;   // block owns 128 q rows; wave owns 32

    const __bf16* kb_base = ws + (size_t)h * HSTRIDE + (size_t)seq * NTILE * TILE_E;
    const __bf16* vt_base = ws + VT_OFF + (size_t)h * HSTRIDE + (size_t)seq * NTILE * TILE_E;

    const float qscale = 0.125f * 1.44269504088896340736f; // 1/sqrt(64) * log2(e)

    // Q fragments for 2 q-subtiles: row = q0 + wave*32 + u*16 + a, d = 8g + 32c + [0..8)
    bf16x8 qf[2][2];
    #pragma unroll
    for (int u = 0; u < 2; ++u) {
        const float* qp = Q + (size_t)(q0 + wave * 32 + u * 16 + a) * HD + h * HEAD_DIM + g * 8;
        #pragma unroll
        for (int c = 0; c < 2; ++c) {
            float4 f0 = *reinterpret_cast<const float4*>(qp + 32 * c);
            float4 f1 = *reinterpret_cast<const float4*>(qp + 32 * c + 4);
            qf[u][c][0] = (__bf16)(f0.x * qscale); qf[u][c][1] = (__bf16)(f0.y * qscale);
            qf[u][c][2] = (__bf16)(f0.z * qscale); qf[u][c][3] = (__bf16)(f0.w * qscale);
            qf[u][c][4] = (__bf16)(f1.x * qscale); qf[u][c][5] = (__bf16)(f1.y * qscale);
            qf[u][c][6] = (__bf16)(f1.z * qscale); qf[u][c][7] = (__bf16)(f1.w * qscale);
        }
    }

    f32x4 o_acc[2][4];
    #pragma unroll
    for (int u = 0; u < 2; ++u)
        #pragma unroll
        for (int dt = 0; dt < 4; ++dt) o_acc[u][dt] = (f32x4){0.f, 0.f, 0.f, 0.f};
    f32x4 l_acc[2] = {(f32x4){0.f, 0.f, 0.f, 0.f}, (f32x4){0.f, 0.f, 0.f, 0.f}};

    bf16x8 ones;
    #pragma unroll
    for (int e = 0; e < 8; ++e) ones[e] = (__bf16)1.0f;

    const f32x4 minit = (f32x4){-FIXED_M, -FIXED_M, -FIXED_M, -FIXED_M};
    const int loff = lane * 8;   // this lane's 8-elem slot within a 512-elem fragment

    #pragma unroll 2
    for (int it = 0; it < NTILE; ++it) {
        const __bf16* kb = kb_base + (size_t)it * TILE_E;
        const __bf16* vb = vt_base + (size_t)it * TILE_E;

        // coalesced 1KB-span fragment loads (L1/L2 served; shared by both q-subtiles)
        bf16x8 kf[8], vf[8];
        #pragma unroll
        for (int f = 0; f < 8; ++f) kf[f] = *reinterpret_cast<const bf16x8*>(kb + f * 512 + loff);
        #pragma unroll
        for (int f = 0; f < 8; ++f) vf[f] = *reinterpret_cast<const bf16x8*>(vb + f * 512 + loff);

        // ---- QK^T (swapped): s[u][t][r] = S^T[kv=16t+4g+r][q=a] - FIXED_M ----
        f32x4 s[2][4];
        __builtin_amdgcn_s_setprio(1);
        #pragma unroll
        for (int t = 0; t < 4; ++t)
            #pragma unroll
            for (int u = 0; u < 2; ++u) {
                s[u][t] = MFMA16(kf[2 * t],     qf[u][0], minit);
                s[u][t] = MFMA16(kf[2 * t + 1], qf[u][1], s[u][t]);
            }
        __builtin_amdgcn_s_setprio(0);

        // ---- fixed-shift softmax: p = exp2(s), raw v_exp_f32 ----
        // pf[u][c] elem b -> kv = 32c + 16(b>>2) + 4g + (b&3)
        bf16x8 pf[2][2];
        #pragma unroll
        for (int u = 0; u < 2; ++u)
            #pragma unroll
            for (int c = 0; c < 2; ++c)
                #pragma unroll
                for (int bb = 0; bb < 8; ++bb)
                    pf[u][c][bb] = (__bf16)__builtin_amdgcn_exp2f(s[u][2 * c + (bb >> 2)][bb & 3]);

        // ---- l row-sum + PV (V fragments shared across q-subtiles) ----
        __builtin_amdgcn_s_setprio(1);
        #pragma unroll
        for (int u = 0; u < 2; ++u) {
            l_acc[u] = MFMA16(pf[u][0], ones, l_acc[u]);
            l_acc[u] = MFMA16(pf[u][1], ones, l_acc[u]);
        }
        #pragma unroll
        for (int dt = 0; dt < 4; ++dt)
            #pragma unroll
            for (int u = 0; u < 2; ++u) {
                o_acc[u][dt] = MFMA16(pf[u][0], vf[2 * dt],     o_acc[u][dt]);
                o_acc[u][dt] = MFMA16(pf[u][1], vf[2 * dt + 1], o_acc[u][dt]);
            }
        __builtin_amdgcn_s_setprio(0);
    }

    // ---- epilogue: O rows q = wave*32 + u*16 + 4g + r, cols d = 16dt + a ----
    #pragma unroll
    for (int u = 0; u < 2; ++u)
        #pragma unroll
        for (int r = 0; r < 4; ++r) {
            const float inv = 1.0f / l_acc[u][r];
            float* op = O + (size_t)(q0 + wave * 32 + u * 16 + 4 * g + r) * HD + h * HEAD_DIM + a;
            #pragma unroll
            for (int dt = 0; dt < 4; ++dt)
                op[16 * dt] = o_acc[u][dt][r] * inv;
        }
}

extern "C" void kernel_launch(void* const* d_in, const int* in_sizes, int n_in,
                              void* d_out, int out_size, void* d_ws, size_t ws_size,
                              hipStream_t stream) {
    const float* q = (const float*)d_in[0];
    const float* k = (const float*)d_in[1];
    const float* v = (const float*)d_in[2];
    float* out = (float*)d_out;
    __bf16* ws = (__bf16*)d_ws;   // 16 MB: 8 MB K-fragments + 8 MB V-fragments

    dim3 pgrid(64, NUM_HEADS);
    prep_kernel<<<pgrid, 256, 0, stream>>>(k, v, ws);
    fattn7_kernel<<<512, 256, 0, stream>>>(q, ws, out);
}

// Round 8
// 35.788 us; speedup vs baseline: 1.4372x; 1.1199x over previous
//
#include <hip/hip_runtime.h>
#include <hip/hip_bf16.h>

#define NUM_HEADS 16
#define HEAD_DIM  64
#define HD        1024   // NUM_HEADS*HEAD_DIM
#define SEQL      1024
#define NTILE     16     // kv tiles per sequence
#define TILE_E    4096   // elements per 64x64 bf16 tile (8 KB)
#define HSTRIDE   (64 * TILE_E)          // 64 tiles per head
#define VT_OFF    (NUM_HEADS * HSTRIDE)  // V-fragment array offset in ws (elems)
#define FIXED_M   12.0f                  // fixed log2-domain shift (max score ~8 sigma)

typedef __bf16 bf16x8 __attribute__((ext_vector_type(8)));
typedef float  f32x4  __attribute__((ext_vector_type(4)));

#define MFMA16(A, B, C) __builtin_amdgcn_mfma_f32_16x16x32_bf16((A), (B), (C), 0, 0, 0)
#define GLOAD_LDS16(gp, lp) \
  __builtin_amdgcn_global_load_lds((const __attribute__((address_space(1))) void*)(gp), \
                                   (__attribute__((address_space(3))) void*)(lp), 16, 0, 0)

// ---------------- prep: fp32 K,V -> bf16 PER-FRAGMENT-CONTIGUOUS tiles ----------------
// K tile: fragment f = t*2+c contiguous 1KB; lane l=(g,a): K[kv0+16t+a][32c+8g..+8]
// V tile: fragment f = dt*2+c contiguous 1KB; lane l=(g,a): elem e =
//         V[kv0 + 32c+16(e>>2)+4g+(e&3)][16dt+a]
// XCD-swizzled grid so each (h,seq) page lands in the L2 of the XCD that consumes it.
__global__ __launch_bounds__(256)
void prep_kernel(const float* __restrict__ K, const float* __restrict__ V,
                 __bf16* __restrict__ ws)
{
    __shared__ __bf16 v_s[64][72];
    const int tid  = threadIdx.x;
    const int bx   = blockIdx.x;                 // 0..1023
    const int orig = (bx & 7) * 128 + (bx >> 3); // XCD x owns orig in [x*128, x*128+128)
    const int h    = orig >> 6;
    const int tile = orig & 63;                  // seq*16 + it
    const int kv0  = tile * 64;
    __bf16* kb = ws + (size_t)h * HSTRIDE + (size_t)tile * TILE_E;
    __bf16* vt = ws + VT_OFF + (size_t)h * HSTRIDE + (size_t)tile * TILE_E;

    #pragma unroll
    for (int i = 0; i < 2; ++i) {
        const int c2 = tid + 256 * i;      // chunk id 0..511
        const int f  = c2 >> 6;
        const int l  = c2 & 63;
        const int g  = l >> 4, aa = l & 15;
        const int t  = f >> 1, cc = f & 1;
        const int r  = 16 * t + aa;
        const int d0 = 32 * cc + 8 * g;

        const float* kp = K + (size_t)(kv0 + r) * HD + h * HEAD_DIM + d0;
        float4 f0 = *(const float4*)kp, f1 = *(const float4*)(kp + 4);
        bf16x8 u = {(__bf16)f0.x, (__bf16)f0.y, (__bf16)f0.z, (__bf16)f0.w,
                    (__bf16)f1.x, (__bf16)f1.y, (__bf16)f1.z, (__bf16)f1.w};
        *reinterpret_cast<bf16x8*>(kb + f * 512 + l * 8) = u;

        const float* vp = V + (size_t)(kv0 + r) * HD + h * HEAD_DIM + d0;
        float4 g0 = *(const float4*)vp, g1 = *(const float4*)(vp + 4);
        bf16x8 w = {(__bf16)g0.x, (__bf16)g0.y, (__bf16)g0.z, (__bf16)g0.w,
                    (__bf16)g1.x, (__bf16)g1.y, (__bf16)g1.z, (__bf16)g1.w};
        *reinterpret_cast<bf16x8*>(&v_s[r][d0]) = w;
    }
    __syncthreads();
    #pragma unroll
    for (int i = 0; i < 2; ++i) {
        const int c2 = tid + 256 * i;
        const int f  = c2 >> 6;
        const int l  = c2 & 63;
        const int g  = l >> 4, aa = l & 15;
        const int dt = f >> 1, cc = f & 1;
        const int d  = 16 * dt + aa;
        bf16x8 w;
        #pragma unroll
        for (int e = 0; e < 8; ++e) {
            const int kvl = 32 * cc + ((e >> 2) << 4) + 4 * g + (e & 3);
            w[e] = v_s[kvl][d];
        }
        *reinterpret_cast<bf16x8*>(vt + f * 512 + l * 8) = w;
    }
}

// ------- attention: QR=32/wave, 3-buffer counted-vmcnt pipeline (T3/T4), raw barriers -------
__global__ __launch_bounds__(256, 4)
void fattn8_kernel(const float* __restrict__ Q, const __bf16* __restrict__ ws,
                   float* __restrict__ O)
{
    __shared__ __bf16 buf[3][2 * TILE_E];   // 3 x 16 KB: [K frags | V frags]

    const int tid  = threadIdx.x;
    const int lane = tid & 63;
    const int wave = tid >> 6;
    const int g    = lane >> 4;
    const int a    = lane & 15;

    // 512 blocks; bijective XCD chunking: XCD x gets orig in [x*64, x*64+64)
    const int b     = blockIdx.x;
    const int orig  = (b & 7) * 64 + (b >> 3);
    const int group = orig >> 3;          // h*4 + seq
    const int qb    = orig & 7;
    const int h     = group >> 2;
    const int seq   = group & 3;
    const int q0    = seq * SEQL + qb * 128;   // block: 128 q rows; wave: 32

    const __bf16* kb_base = ws + (size_t)h * HSTRIDE + (size_t)seq * NTILE * TILE_E;
    const __bf16* vt_base = ws + VT_OFF + (size_t)h * HSTRIDE + (size_t)seq * NTILE * TILE_E;

    const float qscale = 0.125f * 1.44269504088896340736f; // 1/sqrt(64) * log2(e)

    // Q fragments for 2 q-subtiles: row = q0 + wave*32 + u*16 + a, d = 8g + 32c + [0..8)
    bf16x8 qf[2][2];
    #pragma unroll
    for (int u = 0; u < 2; ++u) {
        const float* qp = Q + (size_t)(q0 + wave * 32 + u * 16 + a) * HD + h * HEAD_DIM + g * 8;
        #pragma unroll
        for (int c = 0; c < 2; ++c) {
            float4 f0 = *reinterpret_cast<const float4*>(qp + 32 * c);
            float4 f1 = *reinterpret_cast<const float4*>(qp + 32 * c + 4);
            qf[u][c][0] = (__bf16)(f0.x * qscale); qf[u][c][1] = (__bf16)(f0.y * qscale);
            qf[u][c][2] = (__bf16)(f0.z * qscale); qf[u][c][3] = (__bf16)(f0.w * qscale);
            qf[u][c][4] = (__bf16)(f1.x * qscale); qf[u][c][5] = (__bf16)(f1.y * qscale);
            qf[u][c][6] = (__bf16)(f1.z * qscale); qf[u][c][7] = (__bf16)(f1.w * qscale);
        }
    }

    f32x4 o_acc[2][4];
    #pragma unroll
    for (int u = 0; u < 2; ++u)
        #pragma unroll
        for (int dt = 0; dt < 4; ++dt) o_acc[u][dt] = (f32x4){0.f, 0.f, 0.f, 0.f};
    f32x4 l_acc[2] = {(f32x4){0.f, 0.f, 0.f, 0.f}, (f32x4){0.f, 0.f, 0.f, 0.f}};

    bf16x8 ones;
    #pragma unroll
    for (int e = 0; e < 8; ++e) ones[e] = (__bf16)1.0f;

    const f32x4 minit = (f32x4){-FIXED_M, -FIXED_M, -FIXED_M, -FIXED_M};
    const int lb    = lane * 16;   // byte slot within a 1KB fragment
    const int stid8 = tid * 8;

    // 4 gload_lds insts per wave per stage (vmcnt +=4)
    auto stage = [&](const int bi, int t) {
        const __bf16* ks = kb_base + (size_t)t * TILE_E + stid8;
        const __bf16* vs = vt_base + (size_t)t * TILE_E + stid8;
        GLOAD_LDS16(ks,        &buf[bi][stid8]);
        GLOAD_LDS16(ks + 2048, &buf[bi][2048 + stid8]);
        GLOAD_LDS16(vs,        &buf[bi][TILE_E + stid8]);
        GLOAD_LDS16(vs + 2048, &buf[bi][TILE_E + 2048 + stid8]);
    };

    stage(0, 0);
    stage(1, 1);   // 8 outstanding

    #pragma unroll
    for (int t = 0; t < NTILE; ++t) {
        // wait own tile-t loads (leave t+1 in flight), then barrier => everyone's t data ready
        asm volatile("s_waitcnt vmcnt(4)" ::: "memory");
        __builtin_amdgcn_sched_barrier(0);
        __builtin_amdgcn_s_barrier();
        __builtin_amdgcn_sched_barrier(0);

        // prefetch t+2 into the buffer freed by this barrier (tail re-stages tile 0/1: keeps
        // per-wave vmcnt arithmetic uniform; harmless redundant loads)
        stage((t + 2) % 3, (t + 2) & (NTILE - 1));

        const char* kc = (const char*)&buf[t % 3][0];
        const char* vc = (const char*)&buf[t % 3][TILE_E];

        // ---- QK^T (swapped): s[u][q4][r] = S^T[kv=16q4+4g+r][q=a] - FIXED_M ----
        f32x4 s[2][4];
        __builtin_amdgcn_s_setprio(1);
        #pragma unroll
        for (int q4 = 0; q4 < 4; ++q4) {
            bf16x8 kf0 = *reinterpret_cast<const bf16x8*>(kc + (2 * q4) * 1024 + lb);
            bf16x8 kf1 = *reinterpret_cast<const bf16x8*>(kc + (2 * q4 + 1) * 1024 + lb);
            s[0][q4] = MFMA16(kf0, qf[0][0], minit);
            s[0][q4] = MFMA16(kf1, qf[0][1], s[0][q4]);
            s[1][q4] = MFMA16(kf0, qf[1][0], minit);
            s[1][q4] = MFMA16(kf1, qf[1][1], s[1][q4]);
        }
        __builtin_amdgcn_s_setprio(0);

        // ---- fixed-shift softmax: p = exp2(s), raw v_exp_f32 ----
        // pf[u][c] elem bb -> kv = 32c + 16(bb>>2) + 4g + (bb&3)
        bf16x8 pf[2][2];
        #pragma unroll
        for (int u = 0; u < 2; ++u)
            #pragma unroll
            for (int c = 0; c < 2; ++c)
                #pragma unroll
                for (int bb = 0; bb < 8; ++bb)
                    pf[u][c][bb] = (__bf16)__builtin_amdgcn_exp2f(s[u][2 * c + (bb >> 2)][bb & 3]);

        // ---- l row-sum + PV (V fragments shared across q-subtiles) ----
        __builtin_amdgcn_s_setprio(1);
        #pragma unroll
        for (int u = 0; u < 2; ++u) {
            l_acc[u] = MFMA16(pf[u][0], ones, l_acc[u]);
            l_acc[u] = MFMA16(pf[u][1], ones, l_acc[u]);
        }
        #pragma unroll
        for (int dt = 0; dt < 4; ++dt) {
            bf16x8 vf0 = *reinterpret_cast<const bf16x8*>(vc + (2 * dt) * 1024 + lb);
            bf16x8 vf1 = *reinterpret_cast<const bf16x8*>(vc + (2 * dt + 1) * 1024 + lb);
            #pragma unroll
            for (int u = 0; u < 2; ++u) {
                o_acc[u][dt] = MFMA16(pf[u][0], vf0, o_acc[u][dt]);
                o_acc[u][dt] = MFMA16(pf[u][1], vf1, o_acc[u][dt]);
            }
        }
        __builtin_amdgcn_s_setprio(0);
        // no trailing barrier: next iteration's waitcnt+barrier provides the sync
    }

    // ---- epilogue: O rows q = wave*32 + u*16 + 4g + r, cols d = 16dt + a ----
    #pragma unroll
    for (int u = 0; u < 2; ++u)
        #pragma unroll
        for (int r = 0; r < 4; ++r) {
            const float inv = 1.0f / l_acc[u][r];
            float* op = O + (size_t)(q0 + wave * 32 + u * 16 + 4 * g + r) * HD + h * HEAD_DIM + a;
            #pragma unroll
            for (int dt = 0; dt < 4; ++dt)
                op[16 * dt] = o_acc[u][dt][r] * inv;
        }
}

extern "C" void kernel_launch(void* const* d_in, const int* in_sizes, int n_in,
                              void* d_out, int out_size, void* d_ws, size_t ws_size,
                              hipStream_t stream) {
    const float* q = (const float*)d_in[0];
    const float* k = (const float*)d_in[1];
    const float* v = (const float*)d_in[2];
    float* out = (float*)d_out;
    __bf16* ws = (__bf16*)d_ws;   // 16 MB: 8 MB K-fragments + 8 MB V-fragments

    prep_kernel<<<1024, 256, 0, stream>>>(k, v, ws);
    fattn8_kernel<<<512, 256, 0, stream>>>(q, ws, out);
}